// Round 2
// baseline (5464.693 us; speedup 1.0000x reference)
//
#include <hip/hip_runtime.h>

#define NN 100000
#define EE 600000
#define DD 164
#define HH 2
#define DKK 82
#define EDIM 16
#define TDIM 8
#define STEP 30000
#define NC 20          // EE / STEP
#define FEAT 24        // EDIM + TDIM
#define HID 82         // D/2
#define NG 41          // DD/4 float4 groups

__device__ __forceinline__ float fast_tanh(float x) {
    float e = __expf(2.0f * x);
    return 1.0f - 2.0f * __builtin_amdgcn_rcpf(e + 1.0f);
}

// ---------------- CSR build ----------------

__global__ void __launch_bounds__(256) zero2_kernel(int* __restrict__ a, int* __restrict__ b, int n) {
    int i = blockIdx.x * 256 + threadIdx.x;
    if (i < n) { a[i] = 0; b[i] = 0; }
}

__global__ void __launch_bounds__(256) count_kernel(const int* __restrict__ ei, int* __restrict__ deg) {
    int e = blockIdx.x * 256 + threadIdx.x;
    if (e < EE) atomicAdd(&deg[ei[EE + e]], 1);
}

// single-block exclusive scan of deg[NN] -> off[NN+1]
__global__ void __launch_bounds__(256) scan_kernel(const int* __restrict__ deg, int* __restrict__ off) {
    const int CH = (NN + 255) / 256;   // 391
    int t = threadIdx.x;
    int beg = t * CH, end = min(beg + CH, NN);
    int s = 0;
    for (int i = beg; i < end; ++i) s += deg[i];
    __shared__ int sums[256];
    sums[t] = s;
    __syncthreads();
    for (int d = 1; d < 256; d <<= 1) {
        int val = (t >= d) ? sums[t - d] : 0;
        __syncthreads();
        sums[t] += val;
        __syncthreads();
    }
    int run = (t == 0) ? 0 : sums[t - 1];
    for (int i = beg; i < end; ++i) { off[i] = run; run += deg[i]; }
    if (t == 255) off[NN] = run;
}

__global__ void __launch_bounds__(256) fill_kernel(const int* __restrict__ ei,
                                                   const int* __restrict__ off,
                                                   int* __restrict__ cnt,
                                                   int* __restrict__ elist) {
    int e = blockIdx.x * 256 + threadIdx.x;
    if (e >= EE) return;
    int d = ei[EE + e];
    int p = atomicAdd(&cnt[d], 1);
    elist[off[d] + p] = e;
}

// ---------------- fused score + FiLM MLP per edge ----------------
// writes escore[2e+h] and unscaled vh row m[e][164]

__global__ void __launch_bounds__(256, 2) edge_kernel(
    const float* __restrict__ q, const float* __restrict__ k, const float* __restrict__ v,
    const int* __restrict__ ei,
    const float* __restrict__ edge_attr, const float* __restrict__ edge_time,
    const float* __restrict__ Wt, const float* __restrict__ bt,
    const float* __restrict__ W1, const float* __restrict__ b1,
    const float* __restrict__ W2, const float* __restrict__ b2,
    const float* __restrict__ rel_bias,
    float* __restrict__ escore, float* __restrict__ m)
{
    int e = blockIdx.x * 256 + threadIdx.x;
    if (e >= EE) return;
    int s = ei[e];
    int d = ei[EE + e];

    // ---- attention score ----
    {
        const float4* qr = (const float4*)(q + (size_t)d * DD);
        const float4* kr = (const float4*)(k + (size_t)s * DD);
        float s0 = 0.f, s1 = 0.f;
        #pragma unroll 4
        for (int i = 0; i < 20; ++i) {
            float4 a = qr[i], b = kr[i];
            s0 += a.x * b.x; s0 += a.y * b.y; s0 += a.z * b.z; s0 += a.w * b.w;
        }
        {
            float4 a = qr[20], b = kr[20];
            s0 += a.x * b.x + a.y * b.y;
            s1 += a.z * b.z + a.w * b.w;
        }
        #pragma unroll 4
        for (int i = 21; i < 41; ++i) {
            float4 a = qr[i], b = kr[i];
            s1 += a.x * b.x; s1 += a.y * b.y; s1 += a.z * b.z; s1 += a.w * b.w;
        }
        const float inv_sqrt = 0.11043152607484654f;  // 1/sqrt(82)
        escore[2 * e]     = __expf(s0 * inv_sqrt + rel_bias[0]);
        escore[2 * e + 1] = __expf(s1 * inv_sqrt + rel_bias[1]);
    }

    // ---- feat = [edge_attr(16), time*Wt+bt(8)] ----
    float feat[FEAT];
    const float4* ea4 = (const float4*)(edge_attr + (size_t)e * EDIM);
    #pragma unroll
    for (int i = 0; i < 4; ++i) {
        float4 a = ea4[i];
        feat[4 * i + 0] = a.x; feat[4 * i + 1] = a.y;
        feat[4 * i + 2] = a.z; feat[4 * i + 3] = a.w;
    }
    float t = edge_time[e];
    #pragma unroll
    for (int j = 0; j < TDIM; ++j) feat[EDIM + j] = t * Wt[j] + bt[j];

    // ---- hmid = relu(W1 @ feat + b1) in VGPRs ----
    float hmid[HID];
    #pragma unroll
    for (int o = 0; o < HID; ++o) {
        float acc = b1[o];
        #pragma unroll
        for (int f = 0; f < FEAT; ++f) acc = fmaf(feat[f], W1[o * FEAT + f], acc);
        hmid[o] = fmaxf(acc, 0.f);
    }

    const float4* vrow4 = (const float4*)(v + (size_t)s * DD);
    float4* mrow = (float4*)(m + (size_t)e * DD);

    #pragma unroll 1
    for (int j = 0; j < NG; ++j) {
        float4 vv = vrow4[j];
        float vvals[4] = {vv.x, vv.y, vv.z, vv.w};
        float res[4];
        #pragma unroll
        for (int u = 0; u < 4; ++u) {
            int dd = 4 * j + u;
            float ga = b2[dd];
            float bb = b2[dd + DD];
            #pragma unroll
            for (int o = 0; o < HID; ++o) {
                ga = fmaf(hmid[o], W2[dd * HID + o], ga);
                bb = fmaf(hmid[o], W2[(dd + DD) * HID + o], bb);
            }
            float gamma = fast_tanh(ga);
            float beta  = fast_tanh(bb);
            res[u] = vvals[u] * (1.f + gamma) + beta;   // unscaled vh
        }
        float4 r; r.x = res[0]; r.y = res[1]; r.z = res[2]; r.w = res[3];
        mrow[j] = r;
    }
}

// ---------------- chunk softmax denominator (reciprocal) ----------------

__global__ void __launch_bounds__(256) chunkinv_kernel(
    const float* __restrict__ escore, float* __restrict__ invsum)
{
    int c = blockIdx.x, h = blockIdx.y;
    const float* base = escore + (size_t)c * STEP * 2 + h;
    float acc = 0.f;
    for (int i = threadIdx.x; i < STEP; i += 256) acc += base[2 * i];
    __shared__ float red[256];
    red[threadIdx.x] = acc;
    __syncthreads();
    for (int s2 = 128; s2 > 0; s2 >>= 1) {
        if (threadIdx.x < s2) red[threadIdx.x] += red[threadIdx.x + s2];
        __syncthreads();
    }
    if (threadIdx.x == 0) invsum[c * 2 + h] = 1.0f / red[0];
}

// ---------------- gather: per (node, float4-group) segment sum ----------------

__global__ void __launch_bounds__(256) gather_kernel(
    const float* __restrict__ m, const int* __restrict__ off, const int* __restrict__ elist,
    const float* __restrict__ escore, const float* __restrict__ invsum,
    float* __restrict__ out)
{
    int gid = blockIdx.x * 256 + threadIdx.x;
    if (gid >= NN * NG) return;
    unsigned node = (unsigned)gid / NG;
    unsigned g    = (unsigned)gid % NG;
    int beg = off[node], end = off[node + 1];
    float ax = 0.f, ay = 0.f, az = 0.f, aw = 0.f;
    int d0 = 4 * g;
    for (int idx = beg; idx < end; ++idx) {
        int e = elist[idx];
        unsigned c = (unsigned)e / STEP;
        float a0 = escore[2 * e]     * invsum[2 * c];
        float a1 = escore[2 * e + 1] * invsum[2 * c + 1];
        float4 mv = ((const float4*)(m + (size_t)e * DD))[g];
        ax = fmaf((d0 + 0 < DKK) ? a0 : a1, mv.x, ax);
        ay = fmaf((d0 + 1 < DKK) ? a0 : a1, mv.y, ay);
        az = fmaf((d0 + 2 < DKK) ? a0 : a1, mv.z, az);
        aw = fmaf((d0 + 3 < DKK) ? a0 : a1, mv.w, aw);
    }
    float4 o; o.x = ax; o.y = ay; o.z = az; o.w = aw;
    ((float4*)out)[(size_t)node * NG + g] = o;
}

// ---------------- fallback path (round-1 style, atomics) ----------------

__global__ void __launch_bounds__(256) zero_kernel(float4* __restrict__ p, int n4) {
    int i = blockIdx.x * 256 + threadIdx.x;
    if (i < n4) p[i] = make_float4(0.f, 0.f, 0.f, 0.f);
}

__global__ void __launch_bounds__(256) main_atomic_kernel(
    const float* __restrict__ v, const int* __restrict__ ei,
    const float* __restrict__ edge_attr, const float* __restrict__ edge_time,
    const float* __restrict__ Wt, const float* __restrict__ bt,
    const float* __restrict__ W1, const float* __restrict__ b1,
    const float* __restrict__ W2, const float* __restrict__ b2,
    const float* __restrict__ escore, const float* __restrict__ invsum,
    float* __restrict__ out)
{
    int e = blockIdx.x * 256 + threadIdx.x;
    if (e >= EE) return;
    int s = ei[e];
    int d = ei[EE + e];
    float feat[FEAT];
    const float4* ea4 = (const float4*)(edge_attr + (size_t)e * EDIM);
    #pragma unroll
    for (int i = 0; i < 4; ++i) {
        float4 a = ea4[i];
        feat[4 * i + 0] = a.x; feat[4 * i + 1] = a.y;
        feat[4 * i + 2] = a.z; feat[4 * i + 3] = a.w;
    }
    float t = edge_time[e];
    #pragma unroll
    for (int j = 0; j < TDIM; ++j) feat[EDIM + j] = t * Wt[j] + bt[j];
    float hmid[HID];
    #pragma unroll
    for (int o = 0; o < HID; ++o) {
        float acc = b1[o];
        #pragma unroll
        for (int f = 0; f < FEAT; ++f) acc = fmaf(feat[f], W1[o * FEAT + f], acc);
        hmid[o] = fmaxf(acc, 0.f);
    }
    int c = e / STEP;
    float att0 = escore[2 * e]     * invsum[2 * c];
    float att1 = escore[2 * e + 1] * invsum[2 * c + 1];
    const float4* vrow4 = (const float4*)(v + (size_t)s * DD);
    float* orow = out + (size_t)d * DD;
    #pragma unroll 1
    for (int j = 0; j < NG; ++j) {
        float4 vv = vrow4[j];
        float vvals[4] = {vv.x, vv.y, vv.z, vv.w};
        float res[4];
        #pragma unroll
        for (int u = 0; u < 4; ++u) {
            int dd = 4 * j + u;
            float ga = b2[dd];
            float bb = b2[dd + DD];
            #pragma unroll
            for (int o = 0; o < HID; ++o) {
                ga = fmaf(hmid[o], W2[dd * HID + o], ga);
                bb = fmaf(hmid[o], W2[(dd + DD) * HID + o], bb);
            }
            float gamma = fast_tanh(ga);
            float beta  = fast_tanh(bb);
            float vh = vvals[u] * (1.f + gamma) + beta;
            res[u] = ((dd < DKK) ? att0 : att1) * vh;
        }
        unsafeAtomicAdd(orow + 4 * j + 0, res[0]);
        unsafeAtomicAdd(orow + 4 * j + 1, res[1]);
        unsafeAtomicAdd(orow + 4 * j + 2, res[2]);
        unsafeAtomicAdd(orow + 4 * j + 3, res[3]);
    }
}

__global__ void __launch_bounds__(256) score_kernel(
    const float* __restrict__ q, const float* __restrict__ k,
    const int* __restrict__ ei, const float* __restrict__ rel_bias,
    float* __restrict__ escore)
{
    int e = blockIdx.x * 256 + threadIdx.x;
    if (e >= EE) return;
    int s = ei[e];
    int d = ei[EE + e];
    const float4* qr = (const float4*)(q + (size_t)d * DD);
    const float4* kr = (const float4*)(k + (size_t)s * DD);
    float s0 = 0.f, s1 = 0.f;
    #pragma unroll 4
    for (int i = 0; i < 20; ++i) {
        float4 a = qr[i], b = kr[i];
        s0 += a.x * b.x; s0 += a.y * b.y; s0 += a.z * b.z; s0 += a.w * b.w;
    }
    {
        float4 a = qr[20], b = kr[20];
        s0 += a.x * b.x + a.y * b.y;
        s1 += a.z * b.z + a.w * b.w;
    }
    #pragma unroll 4
    for (int i = 21; i < 41; ++i) {
        float4 a = qr[i], b = kr[i];
        s1 += a.x * b.x; s1 += a.y * b.y; s1 += a.z * b.z; s1 += a.w * b.w;
    }
    const float inv_sqrt = 0.11043152607484654f;
    escore[2 * e]     = __expf(s0 * inv_sqrt + rel_bias[0]);
    escore[2 * e + 1] = __expf(s1 * inv_sqrt + rel_bias[1]);
}

// ---------------- launch ----------------

extern "C" void kernel_launch(void* const* d_in, const int* in_sizes, int n_in,
                              void* d_out, int out_size, void* d_ws, size_t ws_size,
                              hipStream_t stream) {
    const float* q   = (const float*)d_in[0];
    const float* k   = (const float*)d_in[1];
    const float* v   = (const float*)d_in[2];
    const int*   ei  = (const int*)d_in[3];
    const float* ea  = (const float*)d_in[4];
    const float* et  = (const float*)d_in[5];
    const float* Wt  = (const float*)d_in[6];
    const float* bt  = (const float*)d_in[7];
    const float* W1  = (const float*)d_in[8];
    const float* b1  = (const float*)d_in[9];
    const float* W2  = (const float*)d_in[10];
    const float* b2  = (const float*)d_in[11];
    const float* rb  = (const float*)d_in[12];
    float* out = (float*)d_out;

    // ws layout
    float* m      = (float*)d_ws;                       // EE*DD floats (393.6 MB)
    float* escore = m + (size_t)EE * DD;                // 2*EE
    float* invsum = escore + (size_t)2 * EE;            // 64 (padded)
    int*   deg    = (int*)(invsum + 64);                // NN
    int*   off    = deg + NN;                           // NN+1
    int*   cnt    = off + NN + 1;                       // NN
    int*   elist  = cnt + NN;                           // EE

    size_t need = ((size_t)EE * DD + 2 * EE + 64) * 4 +
                  ((size_t)NN * 3 + 1 + EE) * 4;

    if (ws_size >= need) {
        // CSR build
        zero2_kernel<<<(NN + 255) / 256, 256, 0, stream>>>(deg, cnt, NN);
        count_kernel<<<(EE + 255) / 256, 256, 0, stream>>>(ei, deg);
        scan_kernel<<<1, 256, 0, stream>>>(deg, off);
        fill_kernel<<<(EE + 255) / 256, 256, 0, stream>>>(ei, off, cnt, elist);
        // per-edge fused score + MLP
        edge_kernel<<<(EE + 255) / 256, 256, 0, stream>>>(
            q, k, v, ei, ea, et, Wt, bt, W1, b1, W2, b2, rb, escore, m);
        chunkinv_kernel<<<dim3(NC, HH), 256, 0, stream>>>(escore, invsum);
        // segment-sum gather, one write per out element
        int total = NN * NG;
        gather_kernel<<<(total + 255) / 256, 256, 0, stream>>>(
            m, off, elist, escore, invsum, out);
    } else {
        // fallback: round-1 atomic path (escore/invsum fit in any reasonable ws)
        float* escore_f = (float*)d_ws;
        float* invsum_f = escore_f + (size_t)2 * EE;
        int n4 = out_size / 4;
        zero_kernel<<<(n4 + 255) / 256, 256, 0, stream>>>((float4*)out, n4);
        score_kernel<<<(EE + 255) / 256, 256, 0, stream>>>(q, k, ei, rb, escore_f);
        chunkinv_kernel<<<dim3(NC, HH), 256, 0, stream>>>(escore_f, invsum_f);
        main_atomic_kernel<<<(EE + 255) / 256, 256, 0, stream>>>(
            v, ei, ea, et, Wt, bt, W1, b1, W2, b2, escore_f, invsum_f, out);
    }
}

// Round 3
// 1823.514 us; speedup vs baseline: 2.9968x; 2.9968x over previous
//
#include <hip/hip_runtime.h>

#define NN 100000
#define EE 600000
#define DD 164
#define HH 2
#define DKK 82
#define EDIM 16
#define TDIM 8
#define STEP 30000
#define NC 20          // EE / STEP
#define FEAT 24        // EDIM + TDIM
#define HID 82         // D/2
#define NG 41          // DD/4 float4 groups

__device__ __forceinline__ float fast_tanh(float x) {
    float e = __expf(2.0f * x);
    return 1.0f - 2.0f * __builtin_amdgcn_rcpf(e + 1.0f);
}

// ---------------- CSR build ----------------

__global__ void __launch_bounds__(256) zero2_kernel(int* __restrict__ a, int* __restrict__ b, int n) {
    int i = blockIdx.x * 256 + threadIdx.x;
    if (i < n) { a[i] = 0; b[i] = 0; }
}

__global__ void __launch_bounds__(256) count_kernel(const int* __restrict__ ei, int* __restrict__ deg) {
    int e = blockIdx.x * 256 + threadIdx.x;
    if (e < EE) atomicAdd(&deg[ei[EE + e]], 1);
}

// single-block exclusive scan of deg[NN] -> off[NN+1]
__global__ void __launch_bounds__(256) scan_kernel(const int* __restrict__ deg, int* __restrict__ off) {
    const int CH = (NN + 255) / 256;   // 391
    int t = threadIdx.x;
    int beg = t * CH, end = min(beg + CH, NN);
    int s = 0;
    for (int i = beg; i < end; ++i) s += deg[i];
    __shared__ int sums[256];
    sums[t] = s;
    __syncthreads();
    for (int d = 1; d < 256; d <<= 1) {
        int val = (t >= d) ? sums[t - d] : 0;
        __syncthreads();
        sums[t] += val;
        __syncthreads();
    }
    int run = (t == 0) ? 0 : sums[t - 1];
    for (int i = beg; i < end; ++i) { off[i] = run; run += deg[i]; }
    if (t == 255) off[NN] = run;
}

__global__ void __launch_bounds__(256) fill_kernel(const int* __restrict__ ei,
                                                   const int* __restrict__ off,
                                                   int* __restrict__ cnt,
                                                   int* __restrict__ elist) {
    int e = blockIdx.x * 256 + threadIdx.x;
    if (e >= EE) return;
    int d = ei[EE + e];
    int p = atomicAdd(&cnt[d], 1);
    elist[off[d] + p] = e;
}

// ---------------- score + chunk softmax denom ----------------

__global__ void __launch_bounds__(256) score_kernel(
    const float* __restrict__ q, const float* __restrict__ k,
    const int* __restrict__ ei, const float* __restrict__ rel_bias,
    float* __restrict__ escore)
{
    int e = blockIdx.x * 256 + threadIdx.x;
    if (e >= EE) return;
    int s = ei[e];
    int d = ei[EE + e];
    const float4* qr = (const float4*)(q + (size_t)d * DD);
    const float4* kr = (const float4*)(k + (size_t)s * DD);
    float s0 = 0.f, s1 = 0.f;
    #pragma unroll 4
    for (int i = 0; i < 20; ++i) {
        float4 a = qr[i], b = kr[i];
        s0 += a.x * b.x; s0 += a.y * b.y; s0 += a.z * b.z; s0 += a.w * b.w;
    }
    {
        float4 a = qr[20], b = kr[20];
        s0 += a.x * b.x + a.y * b.y;
        s1 += a.z * b.z + a.w * b.w;
    }
    #pragma unroll 4
    for (int i = 21; i < 41; ++i) {
        float4 a = qr[i], b = kr[i];
        s1 += a.x * b.x; s1 += a.y * b.y; s1 += a.z * b.z; s1 += a.w * b.w;
    }
    const float inv_sqrt = 0.11043152607484654f;  // 1/sqrt(82)
    escore[2 * e]     = __expf(s0 * inv_sqrt + rel_bias[0]);
    escore[2 * e + 1] = __expf(s1 * inv_sqrt + rel_bias[1]);
}

__global__ void __launch_bounds__(256) chunkinv_kernel(
    const float* __restrict__ escore, float* __restrict__ invsum)
{
    int c = blockIdx.x, h = blockIdx.y;
    const float* base = escore + (size_t)c * STEP * 2 + h;
    float acc = 0.f;
    for (int i = threadIdx.x; i < STEP; i += 256) acc += base[2 * i];
    __shared__ float red[256];
    red[threadIdx.x] = acc;
    __syncthreads();
    for (int s2 = 128; s2 > 0; s2 >>= 1) {
        if (threadIdx.x < s2) red[threadIdx.x] += red[threadIdx.x + s2];
        __syncthreads();
    }
    if (threadIdx.x == 0) invsum[c * 2 + h] = 1.0f / red[0];
}

__global__ void __launch_bounds__(256) zero_kernel(float4* __restrict__ p, int n4) {
    int i = blockIdx.x * 256 + threadIdx.x;
    if (i < n4) p[i] = make_float4(0.f, 0.f, 0.f, 0.f);
}

// ---------------- main: FiLM MLP + att*vh + LDS segment-reduce + store ----------------
// Edges processed in dst-sorted order (elist). Per-node partial sums are reduced
// in LDS; one plain store per interior node, atomics only for block-boundary nodes.

__global__ void __launch_bounds__(256, 2) main_csr_kernel(
    const float* __restrict__ v, const int* __restrict__ ei,
    const float* __restrict__ edge_attr, const float* __restrict__ edge_time,
    const float* __restrict__ Wt, const float* __restrict__ bt,
    const float* __restrict__ W1, const float* __restrict__ b1,
    const float* __restrict__ W2, const float* __restrict__ b2,
    const float* __restrict__ escore, const float* __restrict__ invsum,
    const int* __restrict__ off, const int* __restrict__ elist,
    float* __restrict__ out)
{
    __shared__ float4 sred[2][256];
    __shared__ int sdst[256];
    int tid = threadIdx.x;
    int gid = blockIdx.x * 256 + tid;
    bool valid = gid < EE;
    int gi = valid ? gid : (EE - 1);
    int e = elist[gi];
    int s = ei[e];
    int d = ei[EE + e];
    sdst[tid] = valid ? d : -1;

    // ---- feat ----
    float feat[FEAT];
    const float4* ea4 = (const float4*)(edge_attr + (size_t)e * EDIM);
    #pragma unroll
    for (int i = 0; i < 4; ++i) {
        float4 a = ea4[i];
        feat[4 * i + 0] = a.x; feat[4 * i + 1] = a.y;
        feat[4 * i + 2] = a.z; feat[4 * i + 3] = a.w;
    }
    float t = edge_time[e];
    #pragma unroll
    for (int j = 0; j < TDIM; ++j) feat[EDIM + j] = t * Wt[j] + bt[j];

    // ---- hmid = relu(W1 @ feat + b1), resident in VGPRs ----
    float hmid[HID];
    #pragma unroll
    for (int o = 0; o < HID; ++o) {
        float acc = b1[o];
        #pragma unroll
        for (int f = 0; f < FEAT; ++f) acc = fmaf(feat[f], W1[o * FEAT + f], acc);
        hmid[o] = fmaxf(acc, 0.f);
    }

    unsigned c = (unsigned)e / STEP;
    float att0 = escore[2 * e]     * invsum[2 * c];
    float att1 = escore[2 * e + 1] * invsum[2 * c + 1];

    __syncthreads();   // sdst visible
    bool leader = valid && (tid == 0 || sdst[tid - 1] != d);
    int seglen = 0;
    bool interior = false;
    float* orow = nullptr;
    if (leader) {
        while (tid + seglen < 256 && sdst[tid + seglen] == d) ++seglen;
        int bs = blockIdx.x * 256;
        interior = (off[d] >= bs) && (off[d + 1] <= bs + 256);
        orow = out + (size_t)d * DD;
    }

    const float4* vrow4 = (const float4*)(v + (size_t)s * DD);

    #pragma unroll 1
    for (int j = 0; j < NG; ++j) {
        float4 vv = vrow4[j];
        float vvals[4] = {vv.x, vv.y, vv.z, vv.w};
        float res[4];
        #pragma unroll
        for (int u = 0; u < 4; ++u) {
            int dd = 4 * j + u;
            float ga = b2[dd];
            float bb = b2[dd + DD];
            #pragma unroll
            for (int o = 0; o < HID; ++o) {
                ga = fmaf(hmid[o], W2[dd * HID + o], ga);
                bb = fmaf(hmid[o], W2[(dd + DD) * HID + o], bb);
            }
            float gamma = fast_tanh(ga);
            float beta  = fast_tanh(bb);
            float vh = vvals[u] * (1.f + gamma) + beta;
            res[u] = ((dd < DKK) ? att0 : att1) * vh;
        }
        float4 r;
        if (valid) { r.x = res[0]; r.y = res[1]; r.z = res[2]; r.w = res[3]; }
        else       { r = make_float4(0.f, 0.f, 0.f, 0.f); }
        sred[j & 1][tid] = r;
        __syncthreads();
        if (leader) {
            float4 a = sred[j & 1][tid];
            for (int t2 = 1; t2 < seglen; ++t2) {
                float4 b = sred[j & 1][tid + t2];
                a.x += b.x; a.y += b.y; a.z += b.z; a.w += b.w;
            }
            if (interior) {
                ((float4*)orow)[j] = a;
            } else {
                unsafeAtomicAdd(orow + 4 * j + 0, a.x);
                unsafeAtomicAdd(orow + 4 * j + 1, a.y);
                unsafeAtomicAdd(orow + 4 * j + 2, a.z);
                unsafeAtomicAdd(orow + 4 * j + 3, a.w);
            }
        }
    }
}

// ---------------- fallback (proved-correct round-1 atomic path) ----------------

__global__ void __launch_bounds__(256) main_atomic_kernel(
    const float* __restrict__ v, const int* __restrict__ ei,
    const float* __restrict__ edge_attr, const float* __restrict__ edge_time,
    const float* __restrict__ Wt, const float* __restrict__ bt,
    const float* __restrict__ W1, const float* __restrict__ b1,
    const float* __restrict__ W2, const float* __restrict__ b2,
    const float* __restrict__ escore, const float* __restrict__ invsum,
    float* __restrict__ out)
{
    int e = blockIdx.x * 256 + threadIdx.x;
    if (e >= EE) return;
    int s = ei[e];
    int d = ei[EE + e];
    float feat[FEAT];
    const float4* ea4 = (const float4*)(edge_attr + (size_t)e * EDIM);
    #pragma unroll
    for (int i = 0; i < 4; ++i) {
        float4 a = ea4[i];
        feat[4 * i + 0] = a.x; feat[4 * i + 1] = a.y;
        feat[4 * i + 2] = a.z; feat[4 * i + 3] = a.w;
    }
    float t = edge_time[e];
    #pragma unroll
    for (int j = 0; j < TDIM; ++j) feat[EDIM + j] = t * Wt[j] + bt[j];
    float hmid[HID];
    #pragma unroll
    for (int o = 0; o < HID; ++o) {
        float acc = b1[o];
        #pragma unroll
        for (int f = 0; f < FEAT; ++f) acc = fmaf(feat[f], W1[o * FEAT + f], acc);
        hmid[o] = fmaxf(acc, 0.f);
    }
    int c = e / STEP;
    float att0 = escore[2 * e]     * invsum[2 * c];
    float att1 = escore[2 * e + 1] * invsum[2 * c + 1];
    const float4* vrow4 = (const float4*)(v + (size_t)s * DD);
    float* orow = out + (size_t)d * DD;
    #pragma unroll 1
    for (int j = 0; j < NG; ++j) {
        float4 vv = vrow4[j];
        float vvals[4] = {vv.x, vv.y, vv.z, vv.w};
        float res[4];
        #pragma unroll
        for (int u = 0; u < 4; ++u) {
            int dd = 4 * j + u;
            float ga = b2[dd];
            float bb = b2[dd + DD];
            #pragma unroll
            for (int o = 0; o < HID; ++o) {
                ga = fmaf(hmid[o], W2[dd * HID + o], ga);
                bb = fmaf(hmid[o], W2[(dd + DD) * HID + o], bb);
            }
            float gamma = fast_tanh(ga);
            float beta  = fast_tanh(bb);
            float vh = vvals[u] * (1.f + gamma) + beta;
            res[u] = ((dd < DKK) ? att0 : att1) * vh;
        }
        unsafeAtomicAdd(orow + 4 * j + 0, res[0]);
        unsafeAtomicAdd(orow + 4 * j + 1, res[1]);
        unsafeAtomicAdd(orow + 4 * j + 2, res[2]);
        unsafeAtomicAdd(orow + 4 * j + 3, res[3]);
    }
}

// ---------------- launch ----------------

extern "C" void kernel_launch(void* const* d_in, const int* in_sizes, int n_in,
                              void* d_out, int out_size, void* d_ws, size_t ws_size,
                              hipStream_t stream) {
    const float* q   = (const float*)d_in[0];
    const float* k   = (const float*)d_in[1];
    const float* v   = (const float*)d_in[2];
    const int*   ei  = (const int*)d_in[3];
    const float* ea  = (const float*)d_in[4];
    const float* et  = (const float*)d_in[5];
    const float* Wt  = (const float*)d_in[6];
    const float* bt  = (const float*)d_in[7];
    const float* W1  = (const float*)d_in[8];
    const float* b1  = (const float*)d_in[9];
    const float* W2  = (const float*)d_in[10];
    const float* b2  = (const float*)d_in[11];
    const float* rb  = (const float*)d_in[12];
    float* out = (float*)d_out;

    // ws layout (small): escore, invsum, CSR arrays  (~8.5 MB total)
    float* escore = (float*)d_ws;                 // 2*EE
    float* invsum = escore + (size_t)2 * EE;      // 64 (padded)
    int*   deg    = (int*)(invsum + 64);          // NN
    int*   off    = deg + NN;                     // NN+1
    int*   cnt    = off + NN + 1;                 // NN
    int*   elist  = cnt + NN;                     // EE

    size_t need = ((size_t)2 * EE + 64) * 4 + ((size_t)3 * NN + 1 + EE) * 4;

    int n4 = out_size / 4;
    zero_kernel<<<(n4 + 255) / 256, 256, 0, stream>>>((float4*)out, n4);
    score_kernel<<<(EE + 255) / 256, 256, 0, stream>>>(q, k, ei, rb, escore);
    chunkinv_kernel<<<dim3(NC, HH), 256, 0, stream>>>(escore, invsum);

    if (ws_size >= need) {
        zero2_kernel<<<(NN + 255) / 256, 256, 0, stream>>>(deg, cnt, NN);
        count_kernel<<<(EE + 255) / 256, 256, 0, stream>>>(ei, deg);
        scan_kernel<<<1, 256, 0, stream>>>(deg, off);
        fill_kernel<<<(EE + 255) / 256, 256, 0, stream>>>(ei, off, cnt, elist);
        main_csr_kernel<<<(EE + 255) / 256, 256, 0, stream>>>(
            v, ei, ea, et, Wt, bt, W1, b1, W2, b2, escore, invsum, off, elist, out);
    } else {
        main_atomic_kernel<<<(EE + 255) / 256, 256, 0, stream>>>(
            v, ei, ea, et, Wt, bt, W1, b1, W2, b2, escore, invsum, out);
    }
}

// Round 4
// 1069.795 us; speedup vs baseline: 5.1082x; 1.7045x over previous
//
#include <hip/hip_runtime.h>

#define NN 100000
#define EE 600000
#define DD 164
#define HH 2
#define DKK 82
#define EDIM 16
#define TDIM 8
#define STEP 30000
#define NC 20          // EE / STEP
#define FEAT 24        // EDIM + TDIM
#define HID 82         // D/2
#define NG 41          // DD/4 float4 groups
#define KP 96          // padded K for MFMA (82 -> 96)
#define MP 336         // padded M (2*164 -> 336)
#define NBLK ((EE + 255) / 256)

typedef __attribute__((ext_vector_type(8))) short short8;
typedef __attribute__((ext_vector_type(4))) float floatx4;

__device__ __forceinline__ float fast_tanh(float x) {
    float e = __expf(2.0f * x);
    return 1.0f - 2.0f * __builtin_amdgcn_rcpf(e + 1.0f);
}

__device__ __forceinline__ short f2bf(float f) {
    union { float f; unsigned u; } x; x.f = f;
    unsigned r = x.u + 0x7fffu + ((x.u >> 16) & 1u);   // RNE
    return (short)(r >> 16);
}

// ---------------- one-time weight prep: W2 -> pair-interleaved bf16, b2 -> permuted ----------------
// W2p[2d+p][k] = bf16(W2[d + p*164][k]), zero-padded to [336][96]; b2p[2d+p] = b2[d+p*164]

__global__ void __launch_bounds__(256) prep_w2_kernel(
    const float* __restrict__ W2, const float* __restrict__ b2,
    short* __restrict__ W2p, float* __restrict__ b2p)
{
    int idx = blockIdx.x * 256 + threadIdx.x;
    if (idx < MP * KP) {
        int m = idx / KP, kk = idx - m * KP;
        float val = 0.f;
        if (m < 2 * DD && kk < HID) {
            int dth = m >> 1, p = m & 1;
            val = W2[(size_t)(dth + p * DD) * HID + kk];
        }
        W2p[idx] = f2bf(val);
    }
    if (idx < MP) {
        float bv = 0.f;
        if (idx < 2 * DD) { int dth = idx >> 1, p = idx & 1; bv = b2[dth + p * DD]; }
        b2p[idx] = bv;
    }
}

// ---------------- CSR build ----------------

__global__ void __launch_bounds__(256) zero2_kernel(int* __restrict__ a, int* __restrict__ b, int n) {
    int i = blockIdx.x * 256 + threadIdx.x;
    if (i < n) { a[i] = 0; b[i] = 0; }
}

__global__ void __launch_bounds__(256) count_kernel(const int* __restrict__ ei, int* __restrict__ deg) {
    int e = blockIdx.x * 256 + threadIdx.x;
    if (e < EE) atomicAdd(&deg[ei[EE + e]], 1);
}

__global__ void __launch_bounds__(256) scan_kernel(const int* __restrict__ deg, int* __restrict__ off) {
    const int CH = (NN + 255) / 256;
    int t = threadIdx.x;
    int beg = t * CH, end = min(beg + CH, NN);
    int s = 0;
    for (int i = beg; i < end; ++i) s += deg[i];
    __shared__ int sums[256];
    sums[t] = s;
    __syncthreads();
    for (int d = 1; d < 256; d <<= 1) {
        int val = (t >= d) ? sums[t - d] : 0;
        __syncthreads();
        sums[t] += val;
        __syncthreads();
    }
    int run = (t == 0) ? 0 : sums[t - 1];
    for (int i = beg; i < end; ++i) { off[i] = run; run += deg[i]; }
    if (t == 255) off[NN] = run;
}

__global__ void __launch_bounds__(256) fill_kernel(const int* __restrict__ ei,
                                                   const int* __restrict__ off,
                                                   int* __restrict__ cnt,
                                                   int* __restrict__ elist) {
    int e = blockIdx.x * 256 + threadIdx.x;
    if (e >= EE) return;
    int d = ei[EE + e];
    int p = atomicAdd(&cnt[d], 1);
    elist[off[d] + p] = e;
}

// ---------------- score + chunk softmax denom ----------------

__global__ void __launch_bounds__(256) score_kernel(
    const float* __restrict__ q, const float* __restrict__ k,
    const int* __restrict__ ei, const float* __restrict__ rel_bias,
    float* __restrict__ escore)
{
    int e = blockIdx.x * 256 + threadIdx.x;
    if (e >= EE) return;
    int s = ei[e];
    int d = ei[EE + e];
    const float4* qr = (const float4*)(q + (size_t)d * DD);
    const float4* kr = (const float4*)(k + (size_t)s * DD);
    float s0 = 0.f, s1 = 0.f;
    #pragma unroll 4
    for (int i = 0; i < 20; ++i) {
        float4 a = qr[i], b = kr[i];
        s0 += a.x * b.x; s0 += a.y * b.y; s0 += a.z * b.z; s0 += a.w * b.w;
    }
    {
        float4 a = qr[20], b = kr[20];
        s0 += a.x * b.x + a.y * b.y;
        s1 += a.z * b.z + a.w * b.w;
    }
    #pragma unroll 4
    for (int i = 21; i < 41; ++i) {
        float4 a = qr[i], b = kr[i];
        s1 += a.x * b.x; s1 += a.y * b.y; s1 += a.z * b.z; s1 += a.w * b.w;
    }
    const float inv_sqrt = 0.11043152607484654f;  // 1/sqrt(82)
    escore[2 * e]     = __expf(s0 * inv_sqrt + rel_bias[0]);
    escore[2 * e + 1] = __expf(s1 * inv_sqrt + rel_bias[1]);
}

__global__ void __launch_bounds__(256) chunkinv_kernel(
    const float* __restrict__ escore, float* __restrict__ invsum)
{
    int c = blockIdx.x, h = blockIdx.y;
    const float* base = escore + (size_t)c * STEP * 2 + h;
    float acc = 0.f;
    for (int i = threadIdx.x; i < STEP; i += 256) acc += base[2 * i];
    __shared__ float red[256];
    red[threadIdx.x] = acc;
    __syncthreads();
    for (int s2 = 128; s2 > 0; s2 >>= 1) {
        if (threadIdx.x < s2) red[threadIdx.x] += red[threadIdx.x + s2];
        __syncthreads();
    }
    if (threadIdx.x == 0) invsum[c * 2 + h] = 1.0f / red[0];
}

__global__ void __launch_bounds__(256) zero_kernel(float4* __restrict__ p, int n4) {
    int i = blockIdx.x * 256 + threadIdx.x;
    if (i < n4) p[i] = make_float4(0.f, 0.f, 0.f, 0.f);
}

// ---------------- main: hmid (VALU) -> LDS bf16 -> MFMA W2 GEMM -> epilogue + segment reduce ----
// GEMM computes gb[m=permuted gamma/beta dim][n=edge in block]:
//   A = W2p (global bf16, [336][96]), B = hmid_lds ([256 edges][96] bf16)
// A-frag (16x16x32): lane holds A[mt*16 + (lane&15)][ks*32 + (lane>>4)*8 + j], j=0..7
// B-frag:            lane holds B'[k][n]: hmid[wavebase + nt*16 + (lane&15)][same k]
// C/D:               col n = lane&15, row m = (lane>>4)*4 + r
// With pair-interleaved W2p rows, lane's 4 C-values = (gamma,beta) for dims d0, d0+1, d0 = mt*8 + (lane>>4)*2.

__global__ void __launch_bounds__(256) main_mfma_kernel(
    const float* __restrict__ v, const int* __restrict__ ei,
    const float* __restrict__ edge_attr, const float* __restrict__ edge_time,
    const float* __restrict__ Wt, const float* __restrict__ bt,
    const float* __restrict__ W1, const float* __restrict__ b1,
    const short* __restrict__ W2p, const float* __restrict__ b2p,
    const float* __restrict__ escore, const float* __restrict__ invsum,
    const int* __restrict__ off, const int* __restrict__ elist,
    float* __restrict__ out)
{
    __shared__ short hmid_lds[256 * KP];   // 48 KB, row-major [edge][k] bf16
    __shared__ float res_lds[256 * 8];     // 8 KB, [edge][8 dims of current mt]
    __shared__ int   sdst[256];
    __shared__ int   ssrc[256];
    __shared__ float satt[512];

    const int tid = threadIdx.x;
    const int gid = blockIdx.x * 256 + tid;
    const bool valid = gid < EE;
    const int gi = valid ? gid : (EE - 1);
    const int e = elist[gi];
    const int s = ei[e];
    const int d = ei[EE + e];
    sdst[tid] = valid ? d : -1;
    ssrc[tid] = s;
    {
        unsigned c = (unsigned)e / STEP;
        satt[2 * tid]     = escore[2 * e]     * invsum[2 * c];
        satt[2 * tid + 1] = escore[2 * e + 1] * invsum[2 * c + 1];
    }

    // ---- feat ----
    float feat[FEAT];
    const float4* ea4 = (const float4*)(edge_attr + (size_t)e * EDIM);
    #pragma unroll
    for (int i = 0; i < 4; ++i) {
        float4 a = ea4[i];
        feat[4 * i + 0] = a.x; feat[4 * i + 1] = a.y;
        feat[4 * i + 2] = a.z; feat[4 * i + 3] = a.w;
    }
    float t = edge_time[e];
    #pragma unroll
    for (int j = 0; j < TDIM; ++j) feat[EDIM + j] = t * Wt[j] + bt[j];

    // ---- hmid in 8-wide chunks -> bf16 -> LDS (low register pressure, no spills) ----
    #pragma unroll 1
    for (int oc = 0; oc < KP / 8; ++oc) {
        union { short h[8]; int4 v4; } pk;
        #pragma unroll
        for (int j = 0; j < 8; ++j) {
            int o = oc * 8 + j;
            float acc = 0.f;
            if (o < HID) {
                acc = b1[o];
                #pragma unroll
                for (int f = 0; f < FEAT; ++f) acc = fmaf(feat[f], W1[o * FEAT + f], acc);
                acc = fmaxf(acc, 0.f);
            }
            pk.h[j] = f2bf(acc);
        }
        *(int4*)&hmid_lds[tid * KP + oc * 8] = pk.v4;
    }
    __syncthreads();

    const int lane = tid & 63;
    const int wavebase = tid & ~63;
    const int lrow = lane & 15;
    const int quad = lane >> 4;

    // ---- B fragments: persistent across the whole mt loop (12 x 4 VGPRs) ----
    short8 bfrag[4][3];
    #pragma unroll
    for (int nt = 0; nt < 4; ++nt)
        #pragma unroll
        for (int ks = 0; ks < 3; ++ks)
            bfrag[nt][ks] = *(const short8*)&hmid_lds[(wavebase + nt * 16 + lrow) * KP + ks * 32 + quad * 8];

    // ---- leader metadata (dst-sorted segments, round-3 proven) ----
    bool leader = valid && (tid == 0 || sdst[tid - 1] != d);
    int seglen = 0;
    bool interior = false;
    float* orow = nullptr;
    if (leader) {
        while (tid + seglen < 256 && sdst[tid + seglen] == d) ++seglen;
        int bs = blockIdx.x * 256;
        interior = (off[d] >= bs) && (off[d + 1] <= bs + 256);
        orow = out + (size_t)d * DD;
    }

    #pragma unroll 1
    for (int mt = 0; mt < 21; ++mt) {
        short8 afrag[3];
        #pragma unroll
        for (int ks = 0; ks < 3; ++ks)
            afrag[ks] = *(const short8*)&W2p[(mt * 16 + lrow) * KP + ks * 32 + quad * 8];

        floatx4 acc[4];
        #pragma unroll
        for (int nt = 0; nt < 4; ++nt) acc[nt] = (floatx4)(0.f);
        #pragma unroll
        for (int ks = 0; ks < 3; ++ks)
            #pragma unroll
            for (int nt = 0; nt < 4; ++nt)
                acc[nt] = __builtin_amdgcn_mfma_f32_16x16x32_bf16(afrag[ks], bfrag[nt][ks], acc[nt], 0, 0, 0);

        float4 bias = *(const float4*)&b2p[mt * 16 + quad * 4];
        int d0 = mt * 8 + quad * 2;

        #pragma unroll
        for (int nt = 0; nt < 4; ++nt) {
            int e_loc = wavebase + nt * 16 + lrow;
            float r0 = 0.f, r1 = 0.f;
            if (d0 < DD) {
                float g0  = fast_tanh(acc[nt][0] + bias.x);
                float be0 = fast_tanh(acc[nt][1] + bias.y);
                float g1  = fast_tanh(acc[nt][2] + bias.z);
                float be1 = fast_tanh(acc[nt][3] + bias.w);
                int s_e = ssrc[e_loc];
                const float* vp = v + (size_t)s_e * DD + d0;
                float v0 = vp[0], v1 = vp[1];
                float a0 = satt[2 * e_loc + (d0 >= DKK ? 1 : 0)];
                float a1 = satt[2 * e_loc + (d0 + 1 >= DKK ? 1 : 0)];
                r0 = a0 * (v0 * (1.f + g0) + be0);
                r1 = a1 * (v1 * (1.f + g1) + be1);
            }
            res_lds[e_loc * 8 + quad * 2]     = r0;
            res_lds[e_loc * 8 + quad * 2 + 1] = r1;
        }
        __syncthreads();

        if (leader) {
            float4 s0 = make_float4(0.f, 0.f, 0.f, 0.f);
            float4 s1 = make_float4(0.f, 0.f, 0.f, 0.f);
            for (int t2 = 0; t2 < seglen; ++t2) {
                const float4* rp = (const float4*)&res_lds[(tid + t2) * 8];
                float4 a = rp[0], b = rp[1];
                s0.x += a.x; s0.y += a.y; s0.z += a.z; s0.w += a.w;
                s1.x += b.x; s1.y += b.y; s1.z += b.z; s1.w += b.w;
            }
            int D0 = mt * 8;
            if (interior) {
                *(float4*)(orow + D0) = s0;
                if (D0 + 4 < DD) *(float4*)(orow + D0 + 4) = s1;
            } else {
                unsafeAtomicAdd(orow + D0 + 0, s0.x);
                unsafeAtomicAdd(orow + D0 + 1, s0.y);
                unsafeAtomicAdd(orow + D0 + 2, s0.z);
                unsafeAtomicAdd(orow + D0 + 3, s0.w);
                if (D0 + 4 < DD) {
                    unsafeAtomicAdd(orow + D0 + 4, s1.x);
                    unsafeAtomicAdd(orow + D0 + 5, s1.y);
                    unsafeAtomicAdd(orow + D0 + 6, s1.z);
                    unsafeAtomicAdd(orow + D0 + 7, s1.w);
                }
            }
        }
        __syncthreads();
    }
}

// ---------------- fallback (proved-correct round-1 atomic path) ----------------

__global__ void __launch_bounds__(256) main_atomic_kernel(
    const float* __restrict__ v, const int* __restrict__ ei,
    const float* __restrict__ edge_attr, const float* __restrict__ edge_time,
    const float* __restrict__ Wt, const float* __restrict__ bt,
    const float* __restrict__ W1, const float* __restrict__ b1,
    const float* __restrict__ W2, const float* __restrict__ b2,
    const float* __restrict__ escore, const float* __restrict__ invsum,
    float* __restrict__ out)
{
    int e = blockIdx.x * 256 + threadIdx.x;
    if (e >= EE) return;
    int s = ei[e];
    int d = ei[EE + e];
    float feat[FEAT];
    const float4* ea4 = (const float4*)(edge_attr + (size_t)e * EDIM);
    #pragma unroll
    for (int i = 0; i < 4; ++i) {
        float4 a = ea4[i];
        feat[4 * i + 0] = a.x; feat[4 * i + 1] = a.y;
        feat[4 * i + 2] = a.z; feat[4 * i + 3] = a.w;
    }
    float t = edge_time[e];
    #pragma unroll
    for (int j = 0; j < TDIM; ++j) feat[EDIM + j] = t * Wt[j] + bt[j];
    float hmid[HID];
    #pragma unroll
    for (int o = 0; o < HID; ++o) {
        float acc = b1[o];
        #pragma unroll
        for (int f = 0; f < FEAT; ++f) acc = fmaf(feat[f], W1[o * FEAT + f], acc);
        hmid[o] = fmaxf(acc, 0.f);
    }
    int c = e / STEP;
    float att0 = escore[2 * e]     * invsum[2 * c];
    float att1 = escore[2 * e + 1] * invsum[2 * c + 1];
    const float4* vrow4 = (const float4*)(v + (size_t)s * DD);
    float* orow = out + (size_t)d * DD;
    #pragma unroll 1
    for (int j = 0; j < NG; ++j) {
        float4 vv = vrow4[j];
        float vvals[4] = {vv.x, vv.y, vv.z, vv.w};
        float res[4];
        #pragma unroll
        for (int u = 0; u < 4; ++u) {
            int dd = 4 * j + u;
            float ga = b2[dd];
            float bb = b2[dd + DD];
            #pragma unroll
            for (int o = 0; o < HID; ++o) {
                ga = fmaf(hmid[o], W2[dd * HID + o], ga);
                bb = fmaf(hmid[o], W2[(dd + DD) * HID + o], bb);
            }
            float gamma = fast_tanh(ga);
            float beta  = fast_tanh(bb);
            float vh = vvals[u] * (1.f + gamma) + beta;
            res[u] = ((dd < DKK) ? att0 : att1) * vh;
        }
        unsafeAtomicAdd(orow + 4 * j + 0, res[0]);
        unsafeAtomicAdd(orow + 4 * j + 1, res[1]);
        unsafeAtomicAdd(orow + 4 * j + 2, res[2]);
        unsafeAtomicAdd(orow + 4 * j + 3, res[3]);
    }
}

// ---------------- launch ----------------

extern "C" void kernel_launch(void* const* d_in, const int* in_sizes, int n_in,
                              void* d_out, int out_size, void* d_ws, size_t ws_size,
                              hipStream_t stream) {
    const float* q   = (const float*)d_in[0];
    const float* k   = (const float*)d_in[1];
    const float* v   = (const float*)d_in[2];
    const int*   ei  = (const int*)d_in[3];
    const float* ea  = (const float*)d_in[4];
    const float* et  = (const float*)d_in[5];
    const float* Wt  = (const float*)d_in[6];
    const float* bt  = (const float*)d_in[7];
    const float* W1  = (const float*)d_in[8];
    const float* b1  = (const float*)d_in[9];
    const float* W2  = (const float*)d_in[10];
    const float* b2  = (const float*)d_in[11];
    const float* rb  = (const float*)d_in[12];
    float* out = (float*)d_out;

    // ws layout (16-B aligned chunks), ~9.7 MB total
    short* W2p    = (short*)d_ws;                       // 336*96 shorts = 64512 B
    float* b2p    = (float*)(W2p + MP * KP);            // 336 floats = 1344 B
    float* escore = b2p + MP;                           // 2*EE
    float* invsum = escore + (size_t)2 * EE;            // 64 (padded)
    int*   deg    = (int*)(invsum + 64);                // NN
    int*   off    = deg + NN;                           // NN+1
    int*   cnt    = off + NN + 1;                       // NN
    int*   elist  = cnt + NN;                           // EE

    size_t need = (size_t)(MP * KP) * 2 + (MP + 2 * EE + 64) * 4 +
                  ((size_t)3 * NN + 1 + EE) * 4;

    int n4 = out_size / 4;
    zero_kernel<<<(n4 + 255) / 256, 256, 0, stream>>>((float4*)out, n4);

    if (ws_size >= need) {
        prep_w2_kernel<<<(MP * KP + 255) / 256, 256, 0, stream>>>(W2, b2, W2p, b2p);
        score_kernel<<<NBLK, 256, 0, stream>>>(q, k, ei, rb, escore);
        chunkinv_kernel<<<dim3(NC, HH), 256, 0, stream>>>(escore, invsum);
        zero2_kernel<<<(NN + 255) / 256, 256, 0, stream>>>(deg, cnt, NN);
        count_kernel<<<NBLK, 256, 0, stream>>>(ei, deg);
        scan_kernel<<<1, 256, 0, stream>>>(deg, off);
        fill_kernel<<<NBLK, 256, 0, stream>>>(ei, off, cnt, elist);
        main_mfma_kernel<<<NBLK, 256, 0, stream>>>(
            v, ei, ea, et, Wt, bt, W1, b1, W2p, b2p, escore, invsum, off, elist, out);
    } else {
        float* escore_f = (float*)d_ws;
        float* invsum_f = escore_f + (size_t)2 * EE;
        score_kernel<<<NBLK, 256, 0, stream>>>(q, k, ei, rb, escore_f);
        chunkinv_kernel<<<dim3(NC, HH), 256, 0, stream>>>(escore_f, invsum_f);
        main_atomic_kernel<<<NBLK, 256, 0, stream>>>(
            v, ei, ea, et, Wt, bt, W1, b1, W2, b2, escore_f, invsum_f, out);
    }
}